// Round 3
// baseline (903.687 us; speedup 1.0000x reference)
//
#include <hip/hip_runtime.h>
#include <hip/hip_bf16.h>
#include <math.h>

#define N_S   512
#define C_S   2048
#define HW_S  128
#define NCLS  751
#define NCLSP 768           // padded to 12*64 for the MFMA GEMM
#define ALPHA 1.2f
#define LAMB  0.5f
#define SIGMA 0.8f
#define BN_EPS 1e-5f
#define NBLK  512           // fused kernel grid: 2 blocks/CU on 256 CUs

typedef __attribute__((ext_vector_type(8))) short short8;   // 8 bf16 = 4 VGPRs
typedef __attribute__((ext_vector_type(4))) float f32x4;

__device__ __forceinline__ unsigned short f2bf(float x) {
    __hip_bfloat16 h = __float2bfloat16(x);
    return *reinterpret_cast<unsigned short*>(&h);
}

// -------------------------------------------------------------- 1. avg pool
// features [N, C, H, W] -> gf (= d_out+1). 16 lanes per (n,c) pair.
// Block 0 also zero-inits the 16 control words (accum, finalize ctr, barriers).
__global__ __launch_bounds__(256) void pool_kernel(const float* __restrict__ feat,
                                                   float* __restrict__ out_gf,
                                                   float* __restrict__ ctrl) {
    if (blockIdx.x == 0 && threadIdx.x < 16) ctrl[threadIdx.x] = 0.0f;
    int pair = blockIdx.x * 16 + (threadIdx.x >> 4);   // n*C + c
    int sub  = threadIdx.x & 15;
    const float4* p = reinterpret_cast<const float4*>(feat + (size_t)pair * HW_S);
    float4 v0 = p[sub];
    float4 v1 = p[sub + 16];
    float s = (v0.x + v0.y + v0.z + v0.w) + (v1.x + v1.y + v1.z + v1.w);
    #pragma unroll
    for (int off = 8; off > 0; off >>= 1) s += __shfl_down(s, off, 16);
    if (sub == 0) out_gf[pair] = s * (1.0f / HW_S);
}

// ---------------------------------------------------- software grid barrier
// One-shot counters (one per sync point, zeroed by pool_kernel each call).
// Mirrors HIP cooperative-groups grid.sync: fence/arrive/spin/fence + s_barrier.
__device__ __forceinline__ void grid_bar(unsigned* __restrict__ bars, int idx) {
    __syncthreads();
    if (threadIdx.x == 0) {
        __threadfence();                                  // release (wbL2)
        atomicAdd(&bars[idx], 1u);
        while (atomicAdd(&bars[idx], 0u) < NBLK) __builtin_amdgcn_s_sleep(1);
        __threadfence();                                  // acquire (invL1/L2)
    }
    __syncthreads();
}

// --------------------------------- 2. fused persistent kernel (everything else)
__global__ __launch_bounds__(256, 2) void fused_kernel(
        const float* __restrict__ gf, const float* __restrict__ gamma,
        const float* __restrict__ weight, const int* __restrict__ targets,
        float* __restrict__ mu, float* __restrict__ scale,
        float* __restrict__ sq, float* __restrict__ atten,
        float* __restrict__ logits, float* __restrict__ G,
        unsigned short* __restrict__ bnnh, unsigned short* __restrict__ wnh,
        float* __restrict__ ctrl, float* __restrict__ out) {
    const int t = threadIdx.x;
    const int b = blockIdx.x;
    unsigned* bars = reinterpret_cast<unsigned*>(ctrl + 8);   // ctrl[8..11]

    __shared__ float red1[8][32];
    __shared__ float red2[8][32];
    __shared__ float sred[4];
    __shared__ float sbc[2];

    // ================= Stage B: BN mean/var (blocks 0..63, 32 channels each)
    if (b < 64) {
        int tc = t & 31, tr = t >> 5;
        int c = b * 32 + tc;
        const float* col = gf + c;
        float sum = 0.f, sumsq = 0.f;
        #pragma unroll 4
        for (int n = tr * 64; n < tr * 64 + 64; ++n) {
            float x = col[(size_t)n * C_S];
            sum += x; sumsq += x * x;
        }
        red1[tr][tc] = sum; red2[tr][tc] = sumsq;
        __syncthreads();
        if (t < 32) {
            float a = 0.f, bb = 0.f;
            #pragma unroll
            for (int r = 0; r < 8; ++r) { a += red1[r][t]; bb += red2[r][t]; }
            int cc = b * 32 + t;
            float m   = a * (1.0f / N_S);
            float var = bb * (1.0f / N_S) - m * m;
            mu[cc]    = m;
            scale[cc] = gamma[cc] / sqrtf(var + BN_EPS);
        }
    }
    grid_bar(bars, 0);

    // ========== Stage C: BN-apply+l2norm (512 rows) || weight l2norm (768 rows)
    for (int task = b; task < N_S + NCLSP; task += NBLK) {
        __syncthreads();                    // protect sred/sbc reuse across iters
        if (task < N_S) {
            int n = task;
            const float* row = gf + (size_t)n * C_S;
            float v[8]; float ss = 0.f;
            #pragma unroll
            for (int k = 0; k < 8; ++k) {
                int c = t + k * 256;
                float x = (row[c] - mu[c]) * scale[c];
                v[k] = x; ss += x * x;
            }
            #pragma unroll
            for (int off = 32; off > 0; off >>= 1) ss += __shfl_down(ss, off, 64);
            if ((t & 63) == 0) sred[t >> 6] = ss;
            __syncthreads();
            if (t == 0) {
                float tot = sred[0] + sred[1] + sred[2] + sred[3];
                float inv = 1.0f / fmaxf(sqrtf(tot), 1e-12f);
                sbc[0] = inv;
                sq[n]  = tot * inv * inv;
            }
            __syncthreads();
            float inv = sbc[0];
            unsigned short* orow = bnnh + (size_t)n * C_S;
            #pragma unroll
            for (int k = 0; k < 8; ++k) orow[t + k * 256] = f2bf(v[k] * inv);
        } else {
            int r = task - N_S;             // 0..767
            unsigned short* orow = wnh + (size_t)r * C_S;
            if (r >= NCLS) {                // zero padding rows
                #pragma unroll
                for (int k = 0; k < 8; ++k) orow[t + k * 256] = 0;
            } else {
                const float* row = weight + (size_t)r * C_S;
                float v[8]; float ss = 0.f;
                #pragma unroll
                for (int k = 0; k < 8; ++k) {
                    float x = row[t + k * 256];
                    v[k] = x; ss += x * x;
                }
                #pragma unroll
                for (int off = 32; off > 0; off >>= 1) ss += __shfl_down(ss, off, 64);
                if ((t & 63) == 0) sred[t >> 6] = ss;
                __syncthreads();
                if (t == 0) sbc[0] = 1.0f / fmaxf(sqrtf(sred[0]+sred[1]+sred[2]+sred[3]), 1e-12f);
                __syncthreads();
                float inv = sbc[0];
                #pragma unroll
                for (int k = 0; k < 8; ++k) orow[t + k * 256] = f2bf(v[k] * inv);
            }
        }
    }
    grid_bar(bars, 1);

    // ================= Stage D: both MFMA GEMMs (640 wave-tiles over 2048 waves)
    {
        int wave = t >> 6, lane = t & 63;
        int gid = b * 4 + wave;
        if (gid < 640) {
            const unsigned short* Ah = bnnh;
            const unsigned short* Bh; float* Cm; int m0, n0, ldc;
            if (gid < 384) {                 // logits = bnn @ wn^T  [512 x 768]
                Bh = wnh;  Cm = logits; m0 = (gid & 31) * 16; n0 = (gid >> 5) * 64; ldc = NCLSP;
            } else {                         // G = bnn @ bnn^T     [512 x 512]
                int g2 = gid - 384;
                Bh = bnnh; Cm = G;      m0 = (g2 & 31) * 16;  n0 = (g2 >> 5) * 64;  ldc = N_S;
            }
            int mrow = m0 + (lane & 15);
            int kq   = (lane >> 4) * 8;
            f32x4 acc0 = {0,0,0,0}, acc1 = {0,0,0,0}, acc2 = {0,0,0,0}, acc3 = {0,0,0,0};
            const unsigned short* arow = Ah + (size_t)mrow * C_S + kq;
            const unsigned short* brow = Bh + (size_t)(n0 + (lane & 15)) * C_S + kq;
            #pragma unroll 2
            for (int k = 0; k < C_S; k += 32) {
                short8 a  = *reinterpret_cast<const short8*>(arow + k);
                short8 b0 = *reinterpret_cast<const short8*>(brow + k);
                short8 b1 = *reinterpret_cast<const short8*>(brow + 16 * C_S + k);
                short8 b2 = *reinterpret_cast<const short8*>(brow + 32 * C_S + k);
                short8 b3 = *reinterpret_cast<const short8*>(brow + 48 * C_S + k);
                acc0 = __builtin_amdgcn_mfma_f32_16x16x32_bf16(a, b0, acc0, 0, 0, 0);
                acc1 = __builtin_amdgcn_mfma_f32_16x16x32_bf16(a, b1, acc1, 0, 0, 0);
                acc2 = __builtin_amdgcn_mfma_f32_16x16x32_bf16(a, b2, acc2, 0, 0, 0);
                acc3 = __builtin_amdgcn_mfma_f32_16x16x32_bf16(a, b3, acc3, 0, 0, 0);
            }
            int ccol  = lane & 15;
            int crow0 = m0 + (lane >> 4) * 4;
            #pragma unroll
            for (int r = 0; r < 4; ++r) {
                float* orow = Cm + (size_t)(crow0 + r) * ldc + n0 + ccol;
                orow[0]  = acc0[r];
                orow[16] = acc1[r];
                orow[32] = acc2[r];
                orow[48] = acc3[r];
            }
        }
    }
    grid_bar(bars, 2);

    // ================= Stage E: softmax -> atten (one row per block)
    {
        int n = b;
        const float* row = logits + (size_t)n * NCLSP;
        float m = -1e30f;
        for (int k = t; k < NCLS; k += 256) m = fmaxf(m, row[k]);
        #pragma unroll
        for (int off = 32; off > 0; off >>= 1) m = fmaxf(m, __shfl_down(m, off, 64));
        if ((t & 63) == 0) sred[t >> 6] = m;
        __syncthreads();
        if (t == 0) sbc[0] = fmaxf(fmaxf(sred[0], sred[1]), fmaxf(sred[2], sred[3]));
        __syncthreads();
        float rm = sbc[0];
        float s = 0.f;
        for (int k = t; k < NCLS; k += 256) s += expf(row[k] - rm);
        #pragma unroll
        for (int off = 32; off > 0; off >>= 1) s += __shfl_down(s, off, 64);
        if ((t & 63) == 0) sred[t >> 6] = s;
        __syncthreads();
        if (t == 0) {
            float ssum = sred[0] + sred[1] + sred[2] + sred[3];
            atten[n] = expf(row[targets[n]] - rm) / ssum;
        }
    }
    grid_bar(bars, 3);

    // ================= Stage F: pairwise reduction + finalize
    {
        float numP = 0.f, denP = 0.f, numN = 0.f, denN = 0.f;
        const float inv_sig2 = 1.0f / (SIGMA * SIGMA);
        for (int p = b * 256 + t; p < N_S * N_S; p += NBLK * 256) {
            int i = p >> 9, j = p & (N_S - 1);
            if (i == j) continue;
            float d2   = fmaxf(sq[i] + sq[j] - 2.0f * G[p], 1e-12f);
            float dist = sqrtf(d2);
            float sneg = fmaxf(ALPHA - dist, 1e-12f);
            float Aij  = fminf(atten[i], atten[j]);
            if (targets[i] == targets[j]) {
                float Wm = expf(-d2 * inv_sig2) * Aij;
                numP += Wm * d2; denP += Wm;
            } else {
                float Wm = sneg * Aij;
                numN += Wm * sneg * sneg; denN += Wm;
            }
        }
        #pragma unroll
        for (int off = 32; off > 0; off >>= 1) {
            numP += __shfl_down(numP, off, 64);
            denP += __shfl_down(denP, off, 64);
            numN += __shfl_down(numN, off, 64);
            denN += __shfl_down(denN, off, 64);
        }
        __syncthreads();                       // sred/red1 free for reuse
        if ((t & 63) == 0) {
            int w = t >> 6;
            red1[0][w*4+0] = numP; red1[0][w*4+1] = denP;
            red1[0][w*4+2] = numN; red1[0][w*4+3] = denN;
        }
        __syncthreads();
        if (t < 4) {
            float s = red1[0][t] + red1[0][4+t] + red1[0][8+t] + red1[0][12+t];
            atomicAdd(&ctrl[t], s);
        }
        __syncthreads();
        if (t == 0) {
            __threadfence();
            unsigned prev = atomicAdd(reinterpret_cast<unsigned*>(ctrl + 4), 1u);
            if (prev == NBLK - 1) {            // last block finalizes
                float a0 = atomicAdd(&ctrl[0], 0.0f);
                float a1 = atomicAdd(&ctrl[1], 0.0f);
                float a2 = atomicAdd(&ctrl[2], 0.0f);
                float a3 = atomicAdd(&ctrl[3], 0.0f);
                float L_P = 0.5f * a0 / a1;
                float L_N = 0.5f * a2 / a3;
                out[0] = (1.0f - LAMB) * L_P + LAMB * L_N;
            }
        }
    }
}

// ---------------------------------------------------------------- launcher
extern "C" void kernel_launch(void* const* d_in, const int* in_sizes, int n_in,
                              void* d_out, int out_size, void* d_ws, size_t ws_size,
                              hipStream_t stream) {
    const float* features = (const float*)d_in[0];
    const int*   targets  = (const int*)d_in[1];
    const float* gamma    = (const float*)d_in[2];
    const float* weight   = (const float*)d_in[3];
    float* out = (float*)d_out;
    float* gf  = out + 1;                    // global_feat lives in d_out directly

    // workspace layout (element offsets; all bf16 arrays 16B-aligned)
    float* ws     = (float*)d_ws;
    float* mu     = ws;                      // 2048
    float* scale  = mu + 2048;               // 2048
    float* sq     = scale + 2048;            // 512
    float* atten  = sq + 512;                // 512
    float* ctrl   = atten + 512;             // 16: [0..3] sums, [4] ctr, [8..11] barriers
    float* logits = ctrl + 16;               // 512*768 = 393216
    float* G      = logits + 393216;         // 512*512 = 262144
    unsigned short* bnnh = (unsigned short*)(G + 262144);   // 512*2048 bf16
    unsigned short* wnh  = bnnh + 1048576;                  // 768*2048 bf16

    hipLaunchKernelGGL(pool_kernel, dim3((N_S * C_S) / 16), dim3(256), 0, stream,
                       features, gf, ctrl);
    hipLaunchKernelGGL(fused_kernel, dim3(NBLK), dim3(256), 0, stream,
                       gf, gamma, weight, targets, mu, scale, sq, atten,
                       logits, G, bnnh, wnh, ctrl, out);
}

// Round 4
// 734.289 us; speedup vs baseline: 1.2307x; 1.2307x over previous
//
#include <hip/hip_runtime.h>
#include <hip/hip_bf16.h>
#include <math.h>

#define N_S   512
#define C_S   2048
#define HW_S  128
#define NCLS  751
#define NCLSP 768           // padded to 12*64 for the MFMA GEMM
#define ALPHA 1.2f
#define LAMB  0.5f
#define SIGMA 0.8f
#define BN_EPS 1e-5f
#define KSPLIT 4
#define KSEG  (C_S / KSPLIT)        // 512

typedef __attribute__((ext_vector_type(8))) short short8;   // 8 bf16 = 4 VGPRs
typedef __attribute__((ext_vector_type(4))) float f32x4;

__device__ __forceinline__ unsigned short f2bf(float x) {
    __hip_bfloat16 h = __float2bfloat16(x);
    return *reinterpret_cast<unsigned short*>(&h);
}

// -------------------------------------------------------------- 1. avg pool
// features [N, C, H, W] -> gf (= d_out+1). 8 lanes per (n,c) pair, 4 float4/lane.
// Block 0 zero-inits the 8 control words (accum + finalize ctr).
__global__ __launch_bounds__(256) void pool_kernel(const float* __restrict__ feat,
                                                   float* __restrict__ out_gf,
                                                   float* __restrict__ ctrl) {
    if (blockIdx.x == 0 && threadIdx.x < 8) ctrl[threadIdx.x] = 0.0f;
    int pair = blockIdx.x * 32 + (threadIdx.x >> 3);   // n*C + c
    int sub  = threadIdx.x & 7;
    const float4* p = reinterpret_cast<const float4*>(feat + (size_t)pair * HW_S);
    float4 v0 = p[sub];
    float4 v1 = p[sub + 8];
    float4 v2 = p[sub + 16];
    float4 v3 = p[sub + 24];
    float s = (v0.x + v0.y + v0.z + v0.w) + (v1.x + v1.y + v1.z + v1.w)
            + (v2.x + v2.y + v2.z + v2.w) + (v3.x + v3.y + v3.z + v3.w);
    #pragma unroll
    for (int off = 4; off > 0; off >>= 1) s += __shfl_down(s, off, 8);
    if (sub == 0) out_gf[pair] = s * (1.0f / HW_S);
}

// -------------------------------------------------------------- 2. BN stats
__global__ __launch_bounds__(256) void meanvar_kernel(const float* __restrict__ gf,
                                                      const float* __restrict__ gamma,
                                                      float* __restrict__ mu_out,
                                                      float* __restrict__ scale_out) {
    int tc = threadIdx.x & 31;      // channel within block
    int tr = threadIdx.x >> 5;      // 0..7 row group
    int c  = blockIdx.x * 32 + tc;
    const float* col = gf + c;
    float sum = 0.f, sumsq = 0.f;
    #pragma unroll 4
    for (int n = tr * 64; n < tr * 64 + 64; ++n) {
        float x = col[(size_t)n * C_S];
        sum += x; sumsq += x * x;
    }
    __shared__ float s1[8][32], s2[8][32];
    s1[tr][tc] = sum; s2[tr][tc] = sumsq;
    __syncthreads();
    if (threadIdx.x < 32) {
        int cc = blockIdx.x * 32 + threadIdx.x;
        float a = 0.f, b = 0.f;
        #pragma unroll
        for (int r = 0; r < 8; ++r) { a += s1[r][threadIdx.x]; b += s2[r][threadIdx.x]; }
        float mu  = a * (1.0f / N_S);
        float var = b * (1.0f / N_S) - mu * mu;
        mu_out[cc]    = mu;
        scale_out[cc] = gamma[cc] / sqrtf(var + BN_EPS);
    }
}

// ------------------- 3. fused BN-apply+l2norm (blocks 0..511) / wnorm (512..1279)
__global__ __launch_bounds__(256) void norm_kernel(const float* __restrict__ gf,
                                                   const float* __restrict__ mu,
                                                   const float* __restrict__ scale,
                                                   const float* __restrict__ w,
                                                   unsigned short* __restrict__ bnnh,
                                                   unsigned short* __restrict__ wnh,
                                                   float* __restrict__ sq) {
    int b = blockIdx.x, t = threadIdx.x;
    __shared__ float red[4];
    __shared__ float sinv;
    if (b < N_S) {
        int n = b;
        const float* row = gf + (size_t)n * C_S;
        float v[8]; float ss = 0.f;
        #pragma unroll
        for (int k = 0; k < 8; ++k) {
            int c = t + k * 256;
            float x = (row[c] - mu[c]) * scale[c];
            v[k] = x; ss += x * x;
        }
        #pragma unroll
        for (int off = 32; off > 0; off >>= 1) ss += __shfl_down(ss, off, 64);
        if ((t & 63) == 0) red[t >> 6] = ss;
        __syncthreads();
        if (t == 0) {
            float tot = red[0] + red[1] + red[2] + red[3];
            float inv = 1.0f / fmaxf(sqrtf(tot), 1e-12f);
            sinv = inv;
            sq[n] = tot * inv * inv;
        }
        __syncthreads();
        float inv = sinv;
        unsigned short* orow = bnnh + (size_t)n * C_S;
        #pragma unroll
        for (int k = 0; k < 8; ++k) orow[t + k * 256] = f2bf(v[k] * inv);
    } else {
        int r = b - N_S;                 // 0..767
        unsigned short* orow = wnh + (size_t)r * C_S;
        if (r >= NCLS) {                 // zero padding rows 751..767
            #pragma unroll
            for (int k = 0; k < 8; ++k) orow[t + k * 256] = 0;
            return;
        }
        const float* row = w + (size_t)r * C_S;
        float v[8]; float ss = 0.f;
        #pragma unroll
        for (int k = 0; k < 8; ++k) {
            float x = row[t + k * 256];
            v[k] = x; ss += x * x;
        }
        #pragma unroll
        for (int off = 32; off > 0; off >>= 1) ss += __shfl_down(ss, off, 64);
        if ((t & 63) == 0) red[t >> 6] = ss;
        __syncthreads();
        if (t == 0) sinv = 1.0f / fmaxf(sqrtf(red[0]+red[1]+red[2]+red[3]), 1e-12f);
        __syncthreads();
        float inv = sinv;
        #pragma unroll
        for (int k = 0; k < 8; ++k) orow[t + k * 256] = f2bf(v[k] * inv);
    }
}

// --------------- 4. merged K-split MFMA GEMMs -> fp32 partials
// gid in [0,2560): gid<1536 -> logits tiles (384 tiles x 4 ksplits),
//                  else     -> Gram tiles  (256 tiles x 4 ksplits).
// Each wave: 16x64 output tile over K=512 segment, writes partial[ks].
__global__ __launch_bounds__(256) void gemm_kernel(const unsigned short* __restrict__ bnnh,
                                                   const unsigned short* __restrict__ wnh,
                                                   float* __restrict__ logits_p,   // [4][512*768]
                                                   float* __restrict__ G_p) {      // [4][512*512]
    int wave = threadIdx.x >> 6, lane = threadIdx.x & 63;
    int gid = blockIdx.x * 4 + wave;
    const unsigned short* Bh; float* Cm; int m0, n0, ldc, ks;
    if (gid < 1536) {
        int tile = gid >> 2; ks = gid & 3;
        Bh = wnh; m0 = (tile & 31) * 16; n0 = (tile >> 5) * 64; ldc = NCLSP;
        Cm = logits_p + (size_t)ks * (N_S * NCLSP);
    } else {
        int g2 = gid - 1536;
        int tile = g2 >> 2; ks = g2 & 3;
        Bh = bnnh; m0 = (tile & 31) * 16; n0 = (tile >> 5) * 64; ldc = N_S;
        Cm = G_p + (size_t)ks * (N_S * N_S);
    }
    int kbase = ks * KSEG;
    int mrow = m0 + (lane & 15);
    int kq   = (lane >> 4) * 8;
    f32x4 acc0 = {0,0,0,0}, acc1 = {0,0,0,0}, acc2 = {0,0,0,0}, acc3 = {0,0,0,0};
    const unsigned short* arow = bnnh + (size_t)mrow * C_S + kbase + kq;
    const unsigned short* brow = Bh + (size_t)(n0 + (lane & 15)) * C_S + kbase + kq;
    #pragma unroll 2
    for (int k = 0; k < KSEG; k += 32) {
        short8 a  = *reinterpret_cast<const short8*>(arow + k);
        short8 b0 = *reinterpret_cast<const short8*>(brow + k);
        short8 b1 = *reinterpret_cast<const short8*>(brow + 16 * C_S + k);
        short8 b2 = *reinterpret_cast<const short8*>(brow + 32 * C_S + k);
        short8 b3 = *reinterpret_cast<const short8*>(brow + 48 * C_S + k);
        acc0 = __builtin_amdgcn_mfma_f32_16x16x32_bf16(a, b0, acc0, 0, 0, 0);
        acc1 = __builtin_amdgcn_mfma_f32_16x16x32_bf16(a, b1, acc1, 0, 0, 0);
        acc2 = __builtin_amdgcn_mfma_f32_16x16x32_bf16(a, b2, acc2, 0, 0, 0);
        acc3 = __builtin_amdgcn_mfma_f32_16x16x32_bf16(a, b3, acc3, 0, 0, 0);
    }
    int ccol  = lane & 15;
    int crow0 = m0 + (lane >> 4) * 4;
    #pragma unroll
    for (int r = 0; r < 4; ++r) {
        float* orow = Cm + (size_t)(crow0 + r) * ldc + n0 + ccol;
        orow[0]  = acc0[r];
        orow[16] = acc1[r];
        orow[32] = acc2[r];
        orow[48] = acc3[r];
    }
}

// ---------------------------------------------- 5. softmax -> atten[n]
__global__ __launch_bounds__(256) void softmax_atten_kernel(const float* __restrict__ logits_p,
                                                            const int* __restrict__ targets,
                                                            float* __restrict__ atten) {
    int n = blockIdx.x, t = threadIdx.x;
    const float* r0 = logits_p + (size_t)n * NCLSP;
    const float* r1 = r0 + (size_t)(N_S * NCLSP);
    const float* r2 = r1 + (size_t)(N_S * NCLSP);
    const float* r3 = r2 + (size_t)(N_S * NCLSP);
    __shared__ float red[4];
    __shared__ float srmax, srsum;
    float m = -1e30f;
    for (int k = t; k < NCLS; k += 256) m = fmaxf(m, r0[k] + r1[k] + r2[k] + r3[k]);
    #pragma unroll
    for (int off = 32; off > 0; off >>= 1) m = fmaxf(m, __shfl_down(m, off, 64));
    if ((t & 63) == 0) red[t >> 6] = m;
    __syncthreads();
    if (t == 0) srmax = fmaxf(fmaxf(red[0], red[1]), fmaxf(red[2], red[3]));
    __syncthreads();
    float rm = srmax;
    float s = 0.f;
    for (int k = t; k < NCLS; k += 256) s += expf(r0[k] + r1[k] + r2[k] + r3[k] - rm);
    #pragma unroll
    for (int off = 32; off > 0; off >>= 1) s += __shfl_down(s, off, 64);
    if ((t & 63) == 0) red[t >> 6] = s;
    __syncthreads();
    if (t == 0) {
        srsum = red[0] + red[1] + red[2] + red[3];
        int tg = targets[n];
        atten[n] = expf(r0[tg] + r1[tg] + r2[tg] + r3[tg] - rm) / srsum;
    }
}

// ------------------------ 6. pairwise loss reduction + fused finalize
// ctrl[0..3] = {numP, denP, numN, denN}; ctrl[4] (as uint) = completion ctr.
__global__ __launch_bounds__(256) void pair_reduce_kernel(const float* __restrict__ G_p,
                                                          const float* __restrict__ sq,
                                                          const float* __restrict__ atten,
                                                          const int* __restrict__ targets,
                                                          float* __restrict__ ctrl,
                                                          float* __restrict__ out) {
    float numP = 0.f, denP = 0.f, numN = 0.f, denN = 0.f;
    const float inv_sig2 = 1.0f / (SIGMA * SIGMA);
    const float* G0 = G_p;
    const float* G1 = G0 + N_S * N_S;
    const float* G2 = G1 + N_S * N_S;
    const float* G3 = G2 + N_S * N_S;
    for (int p = blockIdx.x * 256 + threadIdx.x; p < N_S * N_S; p += 256 * 256) {
        int i = p >> 9, j = p & (N_S - 1);
        if (i == j) continue;                    // off-diagonal mask
        float g    = G0[p] + G1[p] + G2[p] + G3[p];
        float d2   = fmaxf(sq[i] + sq[j] - 2.0f * g, 1e-12f);
        float dist = sqrtf(d2);
        float sneg = fmaxf(ALPHA - dist, 1e-12f);
        float Aij  = fminf(atten[i], atten[j]);
        if (targets[i] == targets[j]) {
            float Wm = expf(-d2 * inv_sig2) * Aij;
            numP += Wm * d2; denP += Wm;
        } else {
            float Wm = sneg * Aij;
            numN += Wm * sneg * sneg; denN += Wm;
        }
    }
    #pragma unroll
    for (int off = 32; off > 0; off >>= 1) {
        numP += __shfl_down(numP, off, 64);
        denP += __shfl_down(denP, off, 64);
        numN += __shfl_down(numN, off, 64);
        denN += __shfl_down(denN, off, 64);
    }
    __shared__ float red[4][4];
    int t = threadIdx.x;
    if ((t & 63) == 0) {
        int w = t >> 6;
        red[w][0] = numP; red[w][1] = denP; red[w][2] = numN; red[w][3] = denN;
    }
    __syncthreads();
    if (t < 4) {
        float s = red[0][t] + red[1][t] + red[2][t] + red[3][t];
        atomicAdd(&ctrl[t], s);
    }
    __syncthreads();
    if (t == 0) {
        __threadfence();
        unsigned prev = atomicAdd(reinterpret_cast<unsigned*>(ctrl + 4), 1u);
        if (prev == gridDim.x - 1) {   // last block: finalize
            float a0 = atomicAdd(&ctrl[0], 0.0f);
            float a1 = atomicAdd(&ctrl[1], 0.0f);
            float a2 = atomicAdd(&ctrl[2], 0.0f);
            float a3 = atomicAdd(&ctrl[3], 0.0f);
            float L_P = 0.5f * a0 / a1;
            float L_N = 0.5f * a2 / a3;
            out[0] = (1.0f - LAMB) * L_P + LAMB * L_N;
        }
    }
}

// ---------------------------------------------------------------- launcher
extern "C" void kernel_launch(void* const* d_in, const int* in_sizes, int n_in,
                              void* d_out, int out_size, void* d_ws, size_t ws_size,
                              hipStream_t stream) {
    const float* features = (const float*)d_in[0];
    const int*   targets  = (const int*)d_in[1];
    const float* gamma    = (const float*)d_in[2];
    const float* weight   = (const float*)d_in[3];
    float* out = (float*)d_out;
    float* gf  = out + 1;                    // global_feat lives in d_out directly

    // workspace layout (element offsets; bf16 arrays 16B-aligned)
    float* ws       = (float*)d_ws;
    float* mu       = ws;                        // 2048
    float* scale    = mu + 2048;                 // 2048
    float* sq       = scale + 2048;              // 512
    float* atten    = sq + 512;                  // 512
    float* ctrl     = atten + 512;               // 16: [0..3] sums, [4] ctr
    float* logits_p = ctrl + 16;                 // 4 * 512*768 = 1572864
    float* G_p      = logits_p + 4 * (N_S * NCLSP);  // 4 * 512*512 = 1048576
    unsigned short* bnnh = (unsigned short*)(G_p + 4 * (N_S * N_S));  // 512*2048 bf16
    unsigned short* wnh  = bnnh + (size_t)N_S * C_S;                  // 768*2048 bf16

    hipLaunchKernelGGL(pool_kernel, dim3((N_S * C_S) / 32), dim3(256), 0, stream,
                       features, gf, ctrl);
    hipLaunchKernelGGL(meanvar_kernel, dim3(C_S / 32), dim3(256), 0, stream,
                       gf, gamma, mu, scale);
    hipLaunchKernelGGL(norm_kernel, dim3(N_S + NCLSP), dim3(256), 0, stream,
                       gf, mu, scale, weight, bnnh, wnh, sq);
    hipLaunchKernelGGL(gemm_kernel, dim3(640), dim3(256), 0, stream,
                       bnnh, wnh, logits_p, G_p);
    hipLaunchKernelGGL(softmax_atten_kernel, dim3(N_S), dim3(256), 0, stream,
                       logits_p, targets, atten);
    hipLaunchKernelGGL(pair_reduce_kernel, dim3(256), dim3(256), 0, stream,
                       G_p, sq, atten, targets, ctrl, out);
}